// Round 7
// baseline (900.415 us; speedup 1.0000x reference)
//
#include <hip/hip_runtime.h>
#include <hip/hip_bf16.h>
#include <stdint.h>

// GraphTripleConv: B=32, O=4096, T=16384, D=H=DOUT=128
// out = [new_obj (B*O*128) | new_p (B*T*128)], f32
#define Bn 32
#define On 4096
#define Tn 16384
#define Dn 128

typedef short short8 __attribute__((ext_vector_type(8)));
typedef float f32x4 __attribute__((ext_vector_type(4)));

__device__ inline short f2bf(float f) {
  union { float f; uint32_t u; } v; v.f = f;
  uint32_t u = v.u;
  uint32_t r = u + 0x7fffu + ((u >> 16) & 1u);  // RNE
  return (short)(r >> 16);
}
__device__ inline float bf2f(unsigned short u) {
  union { uint32_t ui; float f; } cv; cv.ui = ((uint32_t)u) << 16; return cv.f;
}

// ---- weight prep: f32 [K][N] -> bf16 [N][K] (transposed)
__global__ void prep_weights(const float* __restrict__ W1, const float* __restrict__ W2,
                             const float* __restrict__ W3, const float* __restrict__ W4,
                             short* __restrict__ w1t, short* __restrict__ w2t,
                             short* __restrict__ w3t, short* __restrict__ w4t) {
  int i = blockIdx.x * 256 + threadIdx.x;
  if (i < 49152) {
    int n = i / 384, k = i % 384;
    w1t[i] = f2bf(W1[k * 128 + n]);
  } else if (i < 49152 + 32768) {
    int j = i - 49152;
    int n = j / 128, k = j % 128;
    w2t[j] = f2bf(W2[k * 384 + 128 + n]);   // only cols 128..383 live (new_s dead)
  } else if (i < 49152 + 32768 + 16384) {
    int j = i - 81920;
    int n = j / 128, k = j % 128;
    w3t[j] = f2bf(W3[k * 128 + n]);
  } else if (i < 114688) {
    int j = i - 98304;
    int n = j / 128, k = j % 128;
    w4t[j] = f2bf(W4[k * 128 + n]);
  }
}

// ---- fused counting sort: per-batch hist+scan+scatter entirely in LDS
__global__ __launch_bounds__(1024) void sort_kernel(
    const int* __restrict__ edges, int* __restrict__ hist_g,
    int* __restrict__ offs_g, unsigned short* __restrict__ eidx)
{
  __shared__ int h[4096];
  __shared__ int of[4096];
  __shared__ int sd[1024];
  int b = blockIdx.x, tid = threadIdx.x;
#pragma unroll
  for (int i = 0; i < 4; i++) h[tid + i * 1024] = 0;
  __syncthreads();
  int ov[16];
#pragma unroll
  for (int j = 0; j < 16; j++) {
    int t = j * 1024 + tid;
    ov[j] = edges[((size_t)(b * Tn + t)) * 2 + 1];
    atomicAdd(&h[ov[j]], 1);
  }
  __syncthreads();
  int base = tid * 4;
  int hh[4]; int s = 0;
#pragma unroll
  for (int j = 0; j < 4; j++) { hh[j] = h[base + j]; s += hh[j]; }
  sd[tid] = s;
  int tsum = s;
  for (int off = 1; off < 1024; off <<= 1) {
    __syncthreads();
    int t = (tid >= off) ? sd[tid - off] : 0;
    __syncthreads();
    sd[tid] += t;
  }
  __syncthreads();
  int excl = sd[tid] - tsum + b * Tn;
#pragma unroll
  for (int j = 0; j < 4; j++) {
    of[base + j] = excl;
    offs_g[b * On + base + j] = excl;
    hist_g[b * On + base + j] = hh[j];
    excl += hh[j];
  }
  __syncthreads();
#pragma unroll
  for (int i = 0; i < 4; i++) h[tid + i * 1024] = 0;   // reuse as fill
  __syncthreads();
#pragma unroll
  for (int j = 0; j < 16; j++) {
    int t = j * 1024 + tid;
    int pos = of[ov[j]] + atomicAdd(&h[ov[j]], 1);
    eidx[pos] = (unsigned short)t;
  }
}

// ---- object projection (persistent weights): objSO[r] = [obj[r]@W1s | obj[r]@W1o], bf16
__global__ __launch_bounds__(512, 2) void objproj(
    const float* __restrict__ obj, const short* __restrict__ w1t,
    unsigned short* __restrict__ objSO)
{
  __shared__ __align__(16) char lds[81920];
  const int WOF = 0, AOF = 65536;
  int tid = threadIdx.x;
  {
    int n = tid >> 2, q = tid & 3;
    int swz = (n & 7) << 4;
    const short* s1 = w1t + n * 384 + q * 32;          // W1s: k 0..127
    const short* s2 = w1t + n * 384 + 256 + q * 32;    // W1o: k 256..383
#pragma unroll
    for (int i = 0; i < 4; i++) {
      *(short8*)(lds + WOF + n * 256 + ((q * 64 + i * 16) ^ swz)) = *(const short8*)(s1 + i * 8);
      *(short8*)(lds + WOF + 32768 + n * 256 + ((q * 64 + i * 16) ^ swz)) = *(const short8*)(s2 + i * 8);
    }
  }
  int wave = tid >> 6, lane = tid & 63;
  int l15 = lane & 15, l4 = lane >> 4;
  int mg = wave >> 2, ng = wave & 3;
  int r = tid >> 3, seg = tid & 7;
  int rswz = (r & 7) << 4;

  for (int it = 0; it < 4; it++) {
    int row0 = (blockIdx.x * 4 + it) * 64;
    if (it) __syncthreads();
    {
      const float* src = obj + (size_t)(row0 + r) * Dn + seg * 16;
      float4 v0 = *(const float4*)(src);
      float4 v1 = *(const float4*)(src + 4);
      float4 v2 = *(const float4*)(src + 8);
      float4 v3 = *(const float4*)(src + 12);
      short8 p0, p1;
      p0[0]=f2bf(v0.x); p0[1]=f2bf(v0.y); p0[2]=f2bf(v0.z); p0[3]=f2bf(v0.w);
      p0[4]=f2bf(v1.x); p0[5]=f2bf(v1.y); p0[6]=f2bf(v1.z); p0[7]=f2bf(v1.w);
      p1[0]=f2bf(v2.x); p1[1]=f2bf(v2.y); p1[2]=f2bf(v2.z); p1[3]=f2bf(v2.w);
      p1[4]=f2bf(v3.x); p1[5]=f2bf(v3.y); p1[6]=f2bf(v3.z); p1[7]=f2bf(v3.w);
      *(short8*)(lds + AOF + r * 256 + ((seg * 32) ^ rswz)) = p0;
      *(short8*)(lds + AOF + r * 256 + ((seg * 32 + 16) ^ rswz)) = p1;
    }
    __syncthreads();
#pragma unroll
    for (int half = 0; half < 2; half++) {
      f32x4 acc[2][2] = {};
#pragma unroll
      for (int kk = 0; kk < 4; kk++) {
        short8 a[2], bb[2];
#pragma unroll
        for (int m = 0; m < 2; m++) {
          int row = mg * 32 + m * 16 + l15;
          a[m] = *(short8*)(lds + AOF + row * 256 + ((kk * 64 + 16 * l4) ^ ((row & 7) << 4)));
        }
#pragma unroll
        for (int n = 0; n < 2; n++) {
          int nr = ng * 32 + n * 16 + l15;
          bb[n] = *(short8*)(lds + WOF + half * 32768 + nr * 256 + ((kk * 64 + 16 * l4) ^ ((nr & 7) << 4)));
        }
#pragma unroll
        for (int m = 0; m < 2; m++)
#pragma unroll
          for (int n = 0; n < 2; n++)
            acc[m][n] = __builtin_amdgcn_mfma_f32_16x16x32_bf16(a[m], bb[n], acc[m][n], 0, 0, 0);
      }
#pragma unroll
      for (int n = 0; n < 2; n++) {
        int col = ng * 32 + n * 16 + l15;
#pragma unroll
        for (int m = 0; m < 2; m++)
#pragma unroll
          for (int rr = 0; rr < 4; rr++) {
            int row = mg * 32 + m * 16 + l4 * 4 + rr;
            objSO[(size_t)(row0 + row) * 256 + half * 128 + col] =
                (unsigned short)f2bf(acc[m][n][rr]);
          }
      }
    }
  }
}

// ---- edge MLP v7: weights in REGISTERS, LDS only A/h1/g (48KB -> 3 blocks/CU).
// grid 768 (3/CU), 512 thr (8 waves: 2mg x 4ng), grid-strided 64-row tiles.
// 2 barriers per tile.
#define NT_TOTAL 8192
#define GRID_E 768
__global__ __launch_bounds__(512, 6) void edge_mlp(
    const float* __restrict__ pred, const int* __restrict__ edges,
    const unsigned short* __restrict__ objSO,
    const short* __restrict__ w1t, const short* __restrict__ w2t,
    const float* __restrict__ b1, const float* __restrict__ g1, const float* __restrict__ be1,
    const float* __restrict__ b2, const float* __restrict__ g2, const float* __restrict__ be2,
    float* __restrict__ out_p, unsigned short* __restrict__ o_scr)
{
  __shared__ __align__(16) char lds[49152];
  const int ABUF = 0;       // A tile: 64 x 256B, swz
  const int HBUF = 16384;   // h1:     64 x 256B, swz
  const int GOF  = 32768;   // g:      64 x 256B, swz

  const float invs = 1.0f / sqrtf(1.001f);
  int tid = threadIdx.x;
  int wave = tid >> 6, lane = tid & 63;
  int l15 = lane & 15, l4 = lane >> 4;
  int mg = wave >> 2, ng = wave & 3;

  // ---- loop-invariant weight fragments -> registers (from L2, once per block)
  short8 w1r[2][4], w2r[4][4];
#pragma unroll
  for (int n = 0; n < 2; n++)
#pragma unroll
    for (int kk = 0; kk < 4; kk++)
      w1r[n][kk] = *(const short8*)&w1t[(ng * 32 + n * 16 + l15) * 384 + 128 + kk * 32 + 8 * l4];
#pragma unroll
  for (int n = 0; n < 4; n++)
#pragma unroll
    for (int kk = 0; kk < 4; kk++)
      w2r[n][kk] = *(const short8*)&w2t[(ng * 64 + n * 16 + l15) * 128 + kk * 32 + 8 * l4];

  int r = tid >> 3, seg = tid & 7;
  int rswz = (r & 7) << 4;

  float4 pv0, pv1, pv2, pv3;
  short8 sv0, sv1, ov0, ov1;

  auto load_tile = [&](int gt) {
    int b_ = gt >> 8;
    int t = ((gt & 255) << 6) + r;
    const float* src = pred + ((size_t)(b_ * Tn + t)) * Dn + seg * 16;
    pv0 = *(const float4*)(src);
    pv1 = *(const float4*)(src + 4);
    pv2 = *(const float4*)(src + 8);
    pv3 = *(const float4*)(src + 12);
    int2 e = *(const int2*)&edges[((size_t)(b_ * Tn + t)) * 2];
    const unsigned short* srow = objSO + ((size_t)(b_ * On + e.x)) * 256 + seg * 16;
    const unsigned short* orow = objSO + ((size_t)(b_ * On + e.y)) * 256 + 128 + seg * 16;
    sv0 = *(const short8*)(srow);
    sv1 = *(const short8*)(srow + 8);
    ov0 = *(const short8*)(orow);
    ov1 = *(const short8*)(orow + 8);
  };

  auto store_stage = [&]() {
    short8 p0, p1;
    p0[0]=f2bf(pv0.x); p0[1]=f2bf(pv0.y); p0[2]=f2bf(pv0.z); p0[3]=f2bf(pv0.w);
    p0[4]=f2bf(pv1.x); p0[5]=f2bf(pv1.y); p0[6]=f2bf(pv1.z); p0[7]=f2bf(pv1.w);
    p1[0]=f2bf(pv2.x); p1[1]=f2bf(pv2.y); p1[2]=f2bf(pv2.z); p1[3]=f2bf(pv2.w);
    p1[4]=f2bf(pv3.x); p1[5]=f2bf(pv3.y); p1[6]=f2bf(pv3.z); p1[7]=f2bf(pv3.w);
    *(short8*)(lds + ABUF + r * 256 + ((seg * 32) ^ rswz)) = p0;
    *(short8*)(lds + ABUF + r * 256 + ((seg * 32 + 16) ^ rswz)) = p1;
    short8 g0, g1v;
#pragma unroll
    for (int j = 0; j < 8; j++) {
      g0[j]  = f2bf(bf2f((unsigned short)sv0[j]) + bf2f((unsigned short)ov0[j]));
      g1v[j] = f2bf(bf2f((unsigned short)sv1[j]) + bf2f((unsigned short)ov1[j]));
    }
    *(short8*)(lds + GOF + r * 256 + ((seg * 32) ^ rswz)) = g0;
    *(short8*)(lds + GOF + r * 256 + ((seg * 32 + 16) ^ rswz)) = g1v;
  };

  int bid = blockIdx.x;
  int ntiles = (NT_TOTAL - 1 - bid) / GRID_E + 1;

  load_tile(bid);
  store_stage();
  if (ntiles > 1) load_tile(bid + GRID_E);
  __syncthreads();

  for (int k = 0; k < ntiles; ++k) {
    int gt = bid + k * GRID_E;
    int b_ = gt >> 8, t0v = (gt & 255) << 6;

    // ---- GEMM1: A(ABUF) @ w1r -> acc1 (wave tile 32x32)
    f32x4 acc1[2][2] = {};
#pragma unroll
    for (int kk = 0; kk < 4; kk++) {
      short8 a[2];
#pragma unroll
      for (int m = 0; m < 2; m++) {
        int row = mg * 32 + m * 16 + l15;
        a[m] = *(short8*)(lds + ABUF + row * 256 + ((kk * 64 + 16 * l4) ^ ((row & 7) << 4)));
      }
#pragma unroll
      for (int m = 0; m < 2; m++)
#pragma unroll
        for (int n = 0; n < 2; n++)
          acc1[m][n] = __builtin_amdgcn_mfma_f32_16x16x32_bf16(a[m], w1r[n][kk], acc1[m][n], 0, 0, 0);
    }
    // ---- epi1: h1 = relu((acc1 + g)*gs + add) -> HBUF (no ABUF conflict)
#pragma unroll
    for (int n = 0; n < 2; n++) {
      int col = ng * 32 + n * 16 + l15;
      float gs = g1[col] * invs;
      float add = b1[col] * gs + be1[col];
#pragma unroll
      for (int m = 0; m < 2; m++)
#pragma unroll
        for (int rr = 0; rr < 4; rr++) {
          int row = mg * 32 + m * 16 + l4 * 4 + rr;
          float gv = bf2f(*(const unsigned short*)(lds + GOF + row * 256 + ((col * 2) ^ ((row & 7) << 4))));
          float v = fmaxf((acc1[m][n][rr] + gv) * gs + add, 0.0f);
          *(short*)(lds + HBUF + row * 256 + ((col * 2) ^ ((row & 7) << 4))) = f2bf(v);
        }
    }
    __syncthreads();   // B1: GEMM1 A-reads, g-reads, h1-writes all settled

    // ---- stage A/g for tile k+1; issue loads for tile k+2
    if (k + 1 < ntiles) store_stage();
    if (k + 2 < ntiles) load_tile(bid + (k + 2) * GRID_E);

    // ---- GEMM2: h1(HBUF) @ w2r -> out_p / o_scr (wave tile 32x64)
    f32x4 acc2[2][4] = {};
#pragma unroll
    for (int kk = 0; kk < 4; kk++) {
      short8 a[2];
#pragma unroll
      for (int m = 0; m < 2; m++) {
        int row = mg * 32 + m * 16 + l15;
        a[m] = *(short8*)(lds + HBUF + row * 256 + ((kk * 64 + 16 * l4) ^ ((row & 7) << 4)));
      }
#pragma unroll
      for (int m = 0; m < 2; m++)
#pragma unroll
        for (int n = 0; n < 4; n++)
          acc2[m][n] = __builtin_amdgcn_mfma_f32_16x16x32_bf16(a[m], w2r[n][kk], acc2[m][n], 0, 0, 0);
    }
#pragma unroll
    for (int n = 0; n < 4; n++) {
      int colp = ng * 64 + n * 16 + l15;   // 0..255
      int c2 = 128 + colp;
      float gs = g2[c2] * invs;
      float add = b2[c2] * gs + be2[c2];
#pragma unroll
      for (int m = 0; m < 2; m++)
#pragma unroll
        for (int rr = 0; rr < 4; rr++) {
          int row = mg * 32 + m * 16 + l4 * 4 + rr;
          float v = fmaxf(acc2[m][n][rr] * gs + add, 0.0f);
          if (colp < 128) {
            out_p[(size_t)(b_ * Tn + t0v + row) * 128 + colp] = v;
          } else {
            o_scr[(size_t)(b_ * Tn + t0v + row) * 128 + (colp - 128)] =
                (unsigned short)f2bf(v);
          }
        }
    }
    __syncthreads();   // B2: h1 reads done; A(k+1)/g(k+1) visible
  }
}

// ---- object MLP (pooling fused, reg weights): gather-mean from o_scr, GEMM3 -> GEMM4
__global__ __launch_bounds__(256) void obj_mlp(
    const unsigned short* __restrict__ o_scr, const int* __restrict__ hist,
    const int* __restrict__ offs, const unsigned short* __restrict__ eidx,
    float* __restrict__ out_obj,
    const short* __restrict__ w3t, const short* __restrict__ w4t,
    const float* __restrict__ b3, const float* __restrict__ g3, const float* __restrict__ be3,
    const float* __restrict__ b4, const float* __restrict__ g4, const float* __restrict__ be4)
{
  __shared__ short xs[64][136];
  __shared__ short hs[64][136];
  const float invs = 1.0f / sqrtf(1.001f);
  int row0 = blockIdx.x * 64;
  int tid = threadIdx.x;

  {
    int r = tid >> 2, seg = tid & 3;
    int rg = row0 + r;
    int bb_ = rg >> 12;
    int cnt = hist[rg], start = offs[rg];
    float sum[32];
#pragma unroll
    for (int j = 0; j < 32; j++) sum[j] = 0.f;
    for (int k = 0; k < cnt; k++) {
      int t = eidx[start + k];
      const unsigned short* src = o_scr + ((size_t)(bb_ * Tn + t)) * 128 + seg * 32;
#pragma unroll
      for (int i = 0; i < 4; i++) {
        short8 v = *(const short8*)(src + i * 8);
#pragma unroll
        for (int j = 0; j < 8; j++) sum[i * 8 + j] += bf2f((unsigned short)v[j]);
      }
    }
    float ic = 1.0f / fmaxf((float)cnt, 1.0f);
#pragma unroll
    for (int i = 0; i < 4; i++) {
      short8 pk;
#pragma unroll
      for (int j = 0; j < 8; j++) pk[j] = f2bf(sum[i * 8 + j] * ic);
      *(short8*)&xs[r][seg * 32 + i * 8] = pk;
    }
  }
  __syncthreads();

  int wave = tid >> 6, lane = tid & 63;
  int l15 = lane & 15, l4 = lane >> 4;
  int n0 = wave * 32;

  // weights -> registers
  short8 w3r[2][4], w4r[2][4];
#pragma unroll
  for (int n = 0; n < 2; n++)
#pragma unroll
    for (int kk = 0; kk < 4; kk++) {
      w3r[n][kk] = *(const short8*)&w3t[(n0 + n * 16 + l15) * 128 + kk * 32 + 8 * l4];
      w4r[n][kk] = *(const short8*)&w4t[(n0 + n * 16 + l15) * 128 + kk * 32 + 8 * l4];
    }

  f32x4 acc[4][2] = {};
#pragma unroll
  for (int kk = 0; kk < 4; kk++) {
    int k0 = kk * 32;
    short8 a[4];
#pragma unroll
    for (int m = 0; m < 4; m++) a[m] = *(short8*)&xs[m * 16 + l15][k0 + 8 * l4];
#pragma unroll
    for (int m = 0; m < 4; m++)
#pragma unroll
      for (int n = 0; n < 2; n++)
        acc[m][n] = __builtin_amdgcn_mfma_f32_16x16x32_bf16(a[m], w3r[n][kk], acc[m][n], 0, 0, 0);
  }
#pragma unroll
  for (int n = 0; n < 2; n++) {
    int col = n0 + n * 16 + l15;
    float gs = g3[col] * invs;
    float add = b3[col] * gs + be3[col];
#pragma unroll
    for (int m = 0; m < 4; m++)
#pragma unroll
      for (int rr = 0; rr < 4; rr++) {
        float v = fmaxf(acc[m][n][rr] * gs + add, 0.0f);
        hs[m * 16 + l4 * 4 + rr][col] = f2bf(v);
      }
  }
  __syncthreads();

  f32x4 acc2[4][2] = {};
#pragma unroll
  for (int kk = 0; kk < 4; kk++) {
    int k0 = kk * 32;
    short8 a[4];
#pragma unroll
    for (int m = 0; m < 4; m++) a[m] = *(short8*)&hs[m * 16 + l15][k0 + 8 * l4];
#pragma unroll
    for (int m = 0; m < 4; m++)
#pragma unroll
      for (int n = 0; n < 2; n++)
        acc2[m][n] = __builtin_amdgcn_mfma_f32_16x16x32_bf16(a[m], w4r[n][kk], acc2[m][n], 0, 0, 0);
  }
#pragma unroll
  for (int n = 0; n < 2; n++) {
    int col = n0 + n * 16 + l15;
    float gs = g4[col] * invs;
    float add = b4[col] * gs + be4[col];
#pragma unroll
    for (int m = 0; m < 4; m++)
#pragma unroll
      for (int rr = 0; rr < 4; rr++) {
        int row = m * 16 + l4 * 4 + rr;
        float v = fmaxf(acc2[m][n][rr] * gs + add, 0.0f);
        out_obj[(size_t)(row0 + row) * 128 + col] = v;
      }
  }
}

extern "C" void kernel_launch(void* const* d_in, const int* in_sizes, int n_in,
                              void* d_out, int out_size, void* d_ws, size_t ws_size,
                              hipStream_t stream) {
  const float* obj  = (const float*)d_in[0];
  const float* pred = (const float*)d_in[1];
  const int*   edges= (const int*)d_in[2];
  const float* W1 = (const float*)d_in[3];
  const float* b1 = (const float*)d_in[4];
  const float* g1 = (const float*)d_in[5];
  const float* be1= (const float*)d_in[6];
  const float* W2 = (const float*)d_in[7];
  const float* b2 = (const float*)d_in[8];
  const float* g2 = (const float*)d_in[9];
  const float* be2= (const float*)d_in[10];
  const float* W3 = (const float*)d_in[11];
  const float* b3 = (const float*)d_in[12];
  const float* g3 = (const float*)d_in[13];
  const float* be3= (const float*)d_in[14];
  const float* W4 = (const float*)d_in[15];
  const float* b4 = (const float*)d_in[16];
  const float* g4 = (const float*)d_in[17];
  const float* be4= (const float*)d_in[18];

  float* out_obj = (float*)d_out;                           // B*O*128
  float* out_p   = (float*)d_out + (size_t)Bn * On * 128;   // B*T*128
  // objSO (bf16 B*O*256 = 67 MB) lives in the out_obj region (dead until obj_mlp)
  unsigned short* objSO = (unsigned short*)d_out;

  char* ws = (char*)d_ws;
  short* w1t = (short*)(ws);
  short* w2t = (short*)(ws + 49152 * 2);
  short* w3t = (short*)(ws + (49152 + 32768) * 2);
  short* w4t = (short*)(ws + (49152 + 32768 + 16384) * 2);

  const size_t OFF_HIST = 262144;
  const size_t OFF_OFFS = OFF_HIST + 524288;
  const size_t OFF_EIDX = OFF_OFFS + 1048576;     // u16 B*T = 1 MB
  const size_t OFF_OSCR = 4194304;                // bf16 B*T*128 = 128 MiB

  int* hist = (int*)(ws + OFF_HIST);
  int* offs = (int*)(ws + OFF_OFFS);
  unsigned short* eidx = (unsigned short*)(ws + OFF_EIDX);
  unsigned short* o_scr = (unsigned short*)(ws + OFF_OSCR);

  prep_weights<<<448, 256, 0, stream>>>(W1, W2, W3, W4, w1t, w2t, w3t, w4t);
  sort_kernel<<<Bn, 1024, 0, stream>>>(edges, hist, offs, eidx);
  objproj<<<512, 512, 0, stream>>>(obj, w1t, objSO);
  edge_mlp<<<GRID_E, 512, 0, stream>>>(pred, edges, objSO, w1t, w2t,
      b1, g1, be1, b2, g2, be2, out_p, o_scr);
  obj_mlp<<<(Bn * On) / 64, 256, 0, stream>>>(o_scr, hist, offs, eidx, out_obj,
      w3t, w4t, b3, g3, be3, b4, g4, be4);
}

// Round 8
// 484.253 us; speedup vs baseline: 1.8594x; 1.8594x over previous
//
#include <hip/hip_runtime.h>
#include <hip/hip_bf16.h>
#include <stdint.h>

// GraphTripleConv: B=32, O=4096, T=16384, D=H=DOUT=128
// out = [new_obj (B*O*128) | new_p (B*T*128)], f32
#define Bn 32
#define On 4096
#define Tn 16384
#define Dn 128

typedef short short8 __attribute__((ext_vector_type(8)));
typedef float f32x4 __attribute__((ext_vector_type(4)));

__device__ inline short f2bf(float f) {
  union { float f; uint32_t u; } v; v.f = f;
  uint32_t u = v.u;
  uint32_t r = u + 0x7fffu + ((u >> 16) & 1u);  // RNE
  return (short)(r >> 16);
}
__device__ inline float bf2f(unsigned short u) {
  union { uint32_t ui; float f; } cv; cv.ui = ((uint32_t)u) << 16; return cv.f;
}

// raw barrier: LDS-only drain; global loads/stores stay in flight (no vmcnt(0))
#define LBAR() do { \
  asm volatile("s_waitcnt lgkmcnt(0)" ::: "memory"); \
  __builtin_amdgcn_sched_barrier(0); \
  __builtin_amdgcn_s_barrier(); \
} while (0)

// ---- weight prep: f32 [K][N] -> bf16 [N][K] (transposed)
__global__ void prep_weights(const float* __restrict__ W1, const float* __restrict__ W2,
                             const float* __restrict__ W3, const float* __restrict__ W4,
                             short* __restrict__ w1t, short* __restrict__ w2t,
                             short* __restrict__ w3t, short* __restrict__ w4t) {
  int i = blockIdx.x * 256 + threadIdx.x;
  if (i < 49152) {
    int n = i / 384, k = i % 384;
    w1t[i] = f2bf(W1[k * 128 + n]);
  } else if (i < 49152 + 32768) {
    int j = i - 49152;
    int n = j / 128, k = j % 128;
    w2t[j] = f2bf(W2[k * 384 + 128 + n]);   // only cols 128..383 live (new_s dead)
  } else if (i < 49152 + 32768 + 16384) {
    int j = i - 81920;
    int n = j / 128, k = j % 128;
    w3t[j] = f2bf(W3[k * 128 + n]);
  } else if (i < 114688) {
    int j = i - 98304;
    int n = j / 128, k = j % 128;
    w4t[j] = f2bf(W4[k * 128 + n]);
  }
}

// ---- fused counting sort: hist+scan+scatter in LDS; emits per-position (t|s<<16), o
__global__ __launch_bounds__(1024) void sort_kernel(
    const int* __restrict__ edges, unsigned short* __restrict__ hist_g,
    int* __restrict__ offs_g, uint32_t* __restrict__ es4,
    unsigned short* __restrict__ osort)
{
  __shared__ int h[4096];
  __shared__ int of[4096];
  __shared__ int sd[1024];
  int b = blockIdx.x, tid = threadIdx.x;
#pragma unroll
  for (int i = 0; i < 4; i++) h[tid + i * 1024] = 0;
  __syncthreads();
  int ov[16], sv[16];
#pragma unroll
  for (int j = 0; j < 16; j++) {
    int t = j * 1024 + tid;
    int2 e = *(const int2*)&edges[((size_t)(b * Tn + t)) * 2];
    sv[j] = e.x; ov[j] = e.y;
    atomicAdd(&h[ov[j]], 1);
  }
  __syncthreads();
  int base = tid * 4;
  int hh[4]; int s = 0;
#pragma unroll
  for (int j = 0; j < 4; j++) { hh[j] = h[base + j]; s += hh[j]; }
  sd[tid] = s;
  int tsum = s;
  for (int off = 1; off < 1024; off <<= 1) {
    __syncthreads();
    int t = (tid >= off) ? sd[tid - off] : 0;
    __syncthreads();
    sd[tid] += t;
  }
  __syncthreads();
  int excl = sd[tid] - tsum + b * Tn;   // global position base
#pragma unroll
  for (int j = 0; j < 4; j++) {
    of[base + j] = excl;
    offs_g[b * On + base + j] = excl;
    hist_g[b * On + base + j] = (unsigned short)hh[j];
    excl += hh[j];
  }
  __syncthreads();
#pragma unroll
  for (int i = 0; i < 4; i++) h[tid + i * 1024] = 0;   // reuse as fill
  __syncthreads();
#pragma unroll
  for (int j = 0; j < 16; j++) {
    int t = j * 1024 + tid;
    int pos = of[ov[j]] + atomicAdd(&h[ov[j]], 1);
    es4[pos] = (uint32_t)t | ((uint32_t)sv[j] << 16);
    osort[pos] = (unsigned short)ov[j];
  }
}

// ---- object projection (persistent weights): objSO[r] = [obj[r]@W1s | obj[r]@W1o], bf16
__global__ __launch_bounds__(512, 2) void objproj(
    const float* __restrict__ obj, const short* __restrict__ w1t,
    unsigned short* __restrict__ objSO)
{
  __shared__ __align__(16) char lds[81920];
  const int WOF = 0, AOF = 65536;
  int tid = threadIdx.x;
  {
    int n = tid >> 2, q = tid & 3;
    int swz = (n & 7) << 4;
    const short* s1 = w1t + n * 384 + q * 32;          // W1s: k 0..127
    const short* s2 = w1t + n * 384 + 256 + q * 32;    // W1o: k 256..383
#pragma unroll
    for (int i = 0; i < 4; i++) {
      *(short8*)(lds + WOF + n * 256 + ((q * 64 + i * 16) ^ swz)) = *(const short8*)(s1 + i * 8);
      *(short8*)(lds + WOF + 32768 + n * 256 + ((q * 64 + i * 16) ^ swz)) = *(const short8*)(s2 + i * 8);
    }
  }
  int wave = tid >> 6, lane = tid & 63;
  int l15 = lane & 15, l4 = lane >> 4;
  int mg = wave >> 2, ng = wave & 3;
  int r = tid >> 3, seg = tid & 7;
  int rswz = (r & 7) << 4;

  for (int it = 0; it < 4; it++) {
    int row0 = (blockIdx.x * 4 + it) * 64;
    if (it) __syncthreads();
    {
      const float* src = obj + (size_t)(row0 + r) * Dn + seg * 16;
      float4 v0 = *(const float4*)(src);
      float4 v1 = *(const float4*)(src + 4);
      float4 v2 = *(const float4*)(src + 8);
      float4 v3 = *(const float4*)(src + 12);
      short8 p0, p1;
      p0[0]=f2bf(v0.x); p0[1]=f2bf(v0.y); p0[2]=f2bf(v0.z); p0[3]=f2bf(v0.w);
      p0[4]=f2bf(v1.x); p0[5]=f2bf(v1.y); p0[6]=f2bf(v1.z); p0[7]=f2bf(v1.w);
      p1[0]=f2bf(v2.x); p1[1]=f2bf(v2.y); p1[2]=f2bf(v2.z); p1[3]=f2bf(v2.w);
      p1[4]=f2bf(v3.x); p1[5]=f2bf(v3.y); p1[6]=f2bf(v3.z); p1[7]=f2bf(v3.w);
      *(short8*)(lds + AOF + r * 256 + ((seg * 32) ^ rswz)) = p0;
      *(short8*)(lds + AOF + r * 256 + ((seg * 32 + 16) ^ rswz)) = p1;
    }
    __syncthreads();
#pragma unroll
    for (int half = 0; half < 2; half++) {
      f32x4 acc[2][2] = {};
#pragma unroll
      for (int kk = 0; kk < 4; kk++) {
        short8 a[2], bb[2];
#pragma unroll
        for (int m = 0; m < 2; m++) {
          int row = mg * 32 + m * 16 + l15;
          a[m] = *(short8*)(lds + AOF + row * 256 + ((kk * 64 + 16 * l4) ^ ((row & 7) << 4)));
        }
#pragma unroll
        for (int n = 0; n < 2; n++) {
          int nr = ng * 32 + n * 16 + l15;
          bb[n] = *(short8*)(lds + WOF + half * 32768 + nr * 256 + ((kk * 64 + 16 * l4) ^ ((nr & 7) << 4)));
        }
#pragma unroll
        for (int m = 0; m < 2; m++)
#pragma unroll
          for (int n = 0; n < 2; n++)
            acc[m][n] = __builtin_amdgcn_mfma_f32_16x16x32_bf16(a[m], bb[n], acc[m][n], 0, 0, 0);
      }
#pragma unroll
      for (int n = 0; n < 2; n++) {
        int col = ng * 32 + n * 16 + l15;
#pragma unroll
        for (int m = 0; m < 2; m++)
#pragma unroll
          for (int rr = 0; rr < 4; rr++) {
            int row = mg * 32 + m * 16 + l4 * 4 + rr;
            objSO[(size_t)(row0 + row) * 256 + half * 128 + col] =
                (unsigned short)f2bf(acc[m][n][rr]);
          }
      }
    }
  }
}

// ---- edge MLP v8: sorted-order processing, persistent LDS weights, fused pooling.
// grid 256 (1 block/CU), 512 thr, 32 tiles of 64 sorted edge-positions each.
// new_o reduced per object-run in LDS -> one bf16 partial row per (object,tile)
// at the run's global position. Raw lgkm-only barriers keep prefetch in flight.
#define ENT 32
__global__ __launch_bounds__(512, 2) void edge_mlp(
    const float* __restrict__ pred,
    const uint32_t* __restrict__ es4, const unsigned short* __restrict__ osort,
    const unsigned short* __restrict__ objSO,
    const short* __restrict__ w1t, const short* __restrict__ w2t,
    const float* __restrict__ b1, const float* __restrict__ g1, const float* __restrict__ be1,
    const float* __restrict__ b2, const float* __restrict__ g2, const float* __restrict__ be2,
    float* __restrict__ out_p, unsigned short* __restrict__ partial)
{
  __shared__ __align__(16) char lds[147456];
  __shared__ int trowL[2][64];
  __shared__ unsigned short osL[2][64];
  const int W1P = 0;        // 32K: w1p rows 0..127 x 256B swz
  const int W2O = 32768;    // 64K: w2  rows 0..255 x 256B swz
  const int AB0 = 98304;    // 16K  (A / h1 / new_o, per parity)
  const int AB1 = 114688;   // 16K
  const int GOF = 131072;   // 16K: g = objS[s]+objO[o]

  const float invs = 1.0f / sqrtf(1.001f);
  int tid = threadIdx.x;

  // resident weights (once per block)
  {
    int n = tid >> 2, q = tid & 3;
    int swz = (n & 7) << 4;
    const short* src = w1t + n * 384 + 128 + q * 32;
#pragma unroll
    for (int i = 0; i < 4; i++)
      *(short8*)(lds + W1P + n * 256 + ((q * 64 + i * 16) ^ swz)) = *(const short8*)(src + i * 8);
  }
  {
    int n = tid >> 1, q = tid & 1;
    int swz = (n & 7) << 4;
    const short* src = w2t + n * 128 + q * 64;
#pragma unroll
    for (int i = 0; i < 8; i++)
      *(short8*)(lds + W2O + n * 256 + ((q * 128 + i * 16) ^ swz)) = *(const short8*)(src + i * 8);
  }

  int r = tid >> 3, seg = tid & 7;
  int rswz = (r & 7) << 4;

  uint32_t c_ts; int c_o;
  float4 pv0, pv1, pv2, pv3;
  short8 sv0, sv1, ov0, ov1;

  auto load_tile = [&](int gt) {
    int b_ = gt >> 8;
    int p0 = gt << 6;
    c_ts = es4[p0 + r];
    c_o  = osort[p0 + r];
    int t = c_ts & 0xFFFF, s = (int)(c_ts >> 16);
    const float* src = pred + ((size_t)b_ * Tn + t) * Dn + seg * 16;
    pv0 = *(const float4*)(src);
    pv1 = *(const float4*)(src + 4);
    pv2 = *(const float4*)(src + 8);
    pv3 = *(const float4*)(src + 12);
    const unsigned short* srow = objSO + ((size_t)b_ * On + s) * 256 + seg * 16;
    const unsigned short* orow = objSO + ((size_t)b_ * On + c_o) * 256 + 128 + seg * 16;
    sv0 = *(const short8*)(srow);
    sv1 = *(const short8*)(srow + 8);
    ov0 = *(const short8*)(orow);
    ov1 = *(const short8*)(orow + 8);
  };

  auto store_stage = [&](int slot) {
    char* ab = lds + (slot ? AB1 : AB0);
    short8 p0, p1;
    p0[0]=f2bf(pv0.x); p0[1]=f2bf(pv0.y); p0[2]=f2bf(pv0.z); p0[3]=f2bf(pv0.w);
    p0[4]=f2bf(pv1.x); p0[5]=f2bf(pv1.y); p0[6]=f2bf(pv1.z); p0[7]=f2bf(pv1.w);
    p1[0]=f2bf(pv2.x); p1[1]=f2bf(pv2.y); p1[2]=f2bf(pv2.z); p1[3]=f2bf(pv2.w);
    p1[4]=f2bf(pv3.x); p1[5]=f2bf(pv3.y); p1[6]=f2bf(pv3.z); p1[7]=f2bf(pv3.w);
    *(short8*)(ab + r * 256 + ((seg * 32) ^ rswz)) = p0;
    *(short8*)(ab + r * 256 + ((seg * 32 + 16) ^ rswz)) = p1;
    short8 g0, g1v;
#pragma unroll
    for (int j = 0; j < 8; j++) {
      g0[j]  = f2bf(bf2f((unsigned short)sv0[j]) + bf2f((unsigned short)ov0[j]));
      g1v[j] = f2bf(bf2f((unsigned short)sv1[j]) + bf2f((unsigned short)ov1[j]));
    }
    *(short8*)(lds + GOF + r * 256 + ((seg * 32) ^ rswz)) = g0;
    *(short8*)(lds + GOF + r * 256 + ((seg * 32 + 16) ^ rswz)) = g1v;
    if (seg == 0) { trowL[slot][r] = (int)(c_ts & 0xFFFF); osL[slot][r] = (unsigned short)c_o; }
  };

  // segmented reduce of new_o (bf16, 64x128 swizzled in AB[pb]) -> partial rows
  auto reduce_tile = [&](int pb, int p0p) {
    if (tid < 128) {
      const char* nb = lds + (pb ? AB1 : AB0);
      int col = tid;
      float sum = 0.f; int runstart = 0;
      for (int i = 0; i < 64; i++) {
        sum += bf2f(*(const unsigned short*)(nb + i * 256 + ((col * 2) ^ ((i & 7) << 4))));
        if (i == 63 || osL[pb][i + 1] != osL[pb][i]) {
          partial[((size_t)(p0p + runstart)) * 128 + col] = (unsigned short)f2bf(sum);
          sum = 0.f; runstart = i + 1;
        }
      }
    }
  };

  int tile0 = blockIdx.x * ENT;
  load_tile(tile0);
  store_stage(0);
  load_tile(tile0 + 1);
  LBAR();

  int wave = tid >> 6, lane = tid & 63;
  int l15 = lane & 15, l4 = lane >> 4;
  int mg = wave >> 2, ng = wave & 3;
  int cur = 0;

  for (int k = 0; k < ENT; ++k) {
    int gt = tile0 + k;
    int b_ = gt >> 8;
    char* Ac = lds + (cur ? AB1 : AB0);

    // ---- P1: GEMM1 (A[cur] @ w1p, wave 32x32) ; reduce previous tile's new_o
    f32x4 acc1[2][2] = {};
#pragma unroll
    for (int kk = 0; kk < 4; kk++) {
      short8 a[2], bb[2];
#pragma unroll
      for (int m = 0; m < 2; m++) {
        int row = mg * 32 + m * 16 + l15;
        a[m] = *(short8*)(Ac + row * 256 + ((kk * 64 + 16 * l4) ^ ((row & 7) << 4)));
      }
#pragma unroll
      for (int n = 0; n < 2; n++) {
        int nr = ng * 32 + n * 16 + l15;
        bb[n] = *(short8*)(lds + W1P + nr * 256 + ((kk * 64 + 16 * l4) ^ ((nr & 7) << 4)));
      }
#pragma unroll
      for (int m = 0; m < 2; m++)
#pragma unroll
        for (int n = 0; n < 2; n++)
          acc1[m][n] = __builtin_amdgcn_mfma_f32_16x16x32_bf16(a[m], bb[n], acc1[m][n], 0, 0, 0);
    }
    if (k > 0) reduce_tile((k - 1) & 1, (gt - 1) << 6);
    LBAR();   // B1

    // ---- P2: epi1: h1 = relu((acc1+g)*gs+add) -> A[cur] (bf16 swz); reads GOF
#pragma unroll
    for (int n = 0; n < 2; n++) {
      int col = ng * 32 + n * 16 + l15;
      float gs = g1[col] * invs;
      float add = b1[col] * gs + be1[col];
#pragma unroll
      for (int m = 0; m < 2; m++)
#pragma unroll
        for (int rr = 0; rr < 4; rr++) {
          int row = mg * 32 + m * 16 + l4 * 4 + rr;
          float gv = bf2f(*(const unsigned short*)(lds + GOF + row * 256 + ((col * 2) ^ ((row & 7) << 4))));
          float v = fmaxf((acc1[m][n][rr] + gv) * gs + add, 0.0f);
          *(short*)(Ac + row * 256 + ((col * 2) ^ ((row & 7) << 4))) = f2bf(v);
        }
    }
    LBAR();   // B2

    // ---- P3: stage tile k+1 -> A[cur^1]/GOF/slots; issue loads for k+2; GEMM2
    if (k + 1 < ENT) store_stage((k + 1) & 1);
    if (k + 2 < ENT) load_tile(tile0 + k + 2);

    f32x4 acc2[2][4] = {};
#pragma unroll
    for (int kk = 0; kk < 4; kk++) {
      short8 a[2], bb[4];
#pragma unroll
      for (int m = 0; m < 2; m++) {
        int row = mg * 32 + m * 16 + l15;
        a[m] = *(short8*)(Ac + row * 256 + ((kk * 64 + 16 * l4) ^ ((row & 7) << 4)));
      }
#pragma unroll
      for (int n = 0; n < 4; n++) {
        int nr = ng * 64 + n * 16 + l15;
        bb[n] = *(short8*)(lds + W2O + nr * 256 + ((kk * 64 + 16 * l4) ^ ((nr & 7) << 4)));
      }
#pragma unroll
      for (int m = 0; m < 2; m++)
#pragma unroll
        for (int n = 0; n < 4; n++)
          acc2[m][n] = __builtin_amdgcn_mfma_f32_16x16x32_bf16(a[m], bb[n], acc2[m][n], 0, 0, 0);
    }
    LBAR();   // B3 (h1 reads done; staged A/g visible)

    // ---- P4: epi2: cols 0..127 -> out_p[trow]; cols 128..255 -> new_o bf16 into A[cur]
#pragma unroll
    for (int n = 0; n < 4; n++) {
      int colp = ng * 64 + n * 16 + l15;   // 0..255
      int c2 = 128 + colp;
      float gs = g2[c2] * invs;
      float add = b2[c2] * gs + be2[c2];
#pragma unroll
      for (int m = 0; m < 2; m++)
#pragma unroll
        for (int rr = 0; rr < 4; rr++) {
          int row = mg * 32 + m * 16 + l4 * 4 + rr;
          float v = fmaxf(acc2[m][n][rr] * gs + add, 0.0f);
          if (colp < 128) {
            out_p[((size_t)b_ * Tn + trowL[cur][row]) * 128 + colp] = v;
          } else {
            *(short*)(Ac + row * 256 + (((colp - 128) * 2) ^ ((row & 7) << 4))) = f2bf(v);
          }
        }
    }
    LBAR();   // B4 (new_o visible for next P1's reduce)
    cur ^= 1;
  }
  // final tile's reduction
  reduce_tile((ENT - 1) & 1, (tile0 + ENT - 1) << 6);
}

// ---- object MLP: sum partial rows (1-2 per object), /count, GEMM3 -> GEMM4
__global__ __launch_bounds__(256) void obj_mlp(
    const unsigned short* __restrict__ partial, const unsigned short* __restrict__ hist,
    const int* __restrict__ offs, float* __restrict__ out_obj,
    const short* __restrict__ w3t, const short* __restrict__ w4t,
    const float* __restrict__ b3, const float* __restrict__ g3, const float* __restrict__ be3,
    const float* __restrict__ b4, const float* __restrict__ g4, const float* __restrict__ be4)
{
  __shared__ short xs[64][136];
  __shared__ short hs[64][136];
  const float invs = 1.0f / sqrtf(1.001f);
  int row0 = blockIdx.x * 64;
  int tid = threadIdx.x;

  {
    int r = tid >> 2, seg = tid & 3;
    int rg = row0 + r;
    int cnt = (int)hist[rg];
    int start = offs[rg];
    float sum[32];
#pragma unroll
    for (int j = 0; j < 32; j++) sum[j] = 0.f;
    int p = start, pend = start + cnt;
    while (p < pend) {   // partial rows at start, then 64-aligned boundaries
      const unsigned short* src = partial + (size_t)p * 128 + seg * 32;
#pragma unroll
      for (int i = 0; i < 4; i++) {
        short8 v = *(const short8*)(src + i * 8);
#pragma unroll
        for (int j = 0; j < 8; j++) sum[i * 8 + j] += bf2f((unsigned short)v[j]);
      }
      p = ((p >> 6) + 1) << 6;
    }
    float ic = 1.0f / fmaxf((float)cnt, 1.0f);
#pragma unroll
    for (int i = 0; i < 4; i++) {
      short8 pk;
#pragma unroll
      for (int j = 0; j < 8; j++) pk[j] = f2bf(sum[i * 8 + j] * ic);
      *(short8*)&xs[r][seg * 32 + i * 8] = pk;
    }
  }
  __syncthreads();

  int wave = tid >> 6, lane = tid & 63;
  int l15 = lane & 15, l4 = lane >> 4;
  int n0 = wave * 32;

  short8 w3r[2][4], w4r[2][4];
#pragma unroll
  for (int n = 0; n < 2; n++)
#pragma unroll
    for (int kk = 0; kk < 4; kk++) {
      w3r[n][kk] = *(const short8*)&w3t[(n0 + n * 16 + l15) * 128 + kk * 32 + 8 * l4];
      w4r[n][kk] = *(const short8*)&w4t[(n0 + n * 16 + l15) * 128 + kk * 32 + 8 * l4];
    }

  f32x4 acc[4][2] = {};
#pragma unroll
  for (int kk = 0; kk < 4; kk++) {
    int k0 = kk * 32;
    short8 a[4];
#pragma unroll
    for (int m = 0; m < 4; m++) a[m] = *(short8*)&xs[m * 16 + l15][k0 + 8 * l4];
#pragma unroll
    for (int m = 0; m < 4; m++)
#pragma unroll
      for (int n = 0; n < 2; n++)
        acc[m][n] = __builtin_amdgcn_mfma_f32_16x16x32_bf16(a[m], w3r[n][kk], acc[m][n], 0, 0, 0);
  }
#pragma unroll
  for (int n = 0; n < 2; n++) {
    int col = n0 + n * 16 + l15;
    float gs = g3[col] * invs;
    float add = b3[col] * gs + be3[col];
#pragma unroll
    for (int m = 0; m < 4; m++)
#pragma unroll
      for (int rr = 0; rr < 4; rr++) {
        float v = fmaxf(acc[m][n][rr] * gs + add, 0.0f);
        hs[m * 16 + l4 * 4 + rr][col] = f2bf(v);
      }
  }
  __syncthreads();

  f32x4 acc2[4][2] = {};
#pragma unroll
  for (int kk = 0; kk < 4; kk++) {
    int k0 = kk * 32;
    short8 a[4];
#pragma unroll
    for (int m = 0; m < 4; m++) a[m] = *(short8*)&hs[m * 16 + l15][k0 + 8 * l4];
#pragma unroll
    for (int m = 0; m < 4; m++)
#pragma unroll
      for (int n = 0; n < 2; n++)
        acc2[m][n] = __builtin_amdgcn_mfma_f32_16x16x32_bf16(a[m], w4r[n][kk], acc2[m][n], 0, 0, 0);
  }
#pragma unroll
  for (int n = 0; n < 2; n++) {
    int col = n0 + n * 16 + l15;
    float gs = g4[col] * invs;
    float add = b4[col] * gs + be4[col];
#pragma unroll
    for (int m = 0; m < 4; m++)
#pragma unroll
      for (int rr = 0; rr < 4; rr++) {
        int row = m * 16 + l4 * 4 + rr;
        float v = fmaxf(acc2[m][n][rr] * gs + add, 0.0f);
        out_obj[(size_t)(row0 + row) * 128 + col] = v;
      }
  }
}

extern "C" void kernel_launch(void* const* d_in, const int* in_sizes, int n_in,
                              void* d_out, int out_size, void* d_ws, size_t ws_size,
                              hipStream_t stream) {
  const float* obj  = (const float*)d_in[0];
  const float* pred = (const float*)d_in[1];
  const int*   edges= (const int*)d_in[2];
  const float* W1 = (const float*)d_in[3];
  const float* b1 = (const float*)d_in[4];
  const float* g1 = (const float*)d_in[5];
  const float* be1= (const float*)d_in[6];
  const float* W2 = (const float*)d_in[7];
  const float* b2 = (const float*)d_in[8];
  const float* g2 = (const float*)d_in[9];
  const float* be2= (const float*)d_in[10];
  const float* W3 = (const float*)d_in[11];
  const float* b3 = (const float*)d_in[12];
  const float* g3 = (const float*)d_in[13];
  const float* be3= (const float*)d_in[14];
  const float* W4 = (const float*)d_in[15];
  const float* b4 = (const float*)d_in[16];
  const float* g4 = (const float*)d_in[17];
  const float* be4= (const float*)d_in[18];

  float* out_obj = (float*)d_out;                           // B*O*128
  float* out_p   = (float*)d_out + (size_t)Bn * On * 128;   // B*T*128
  // objSO (bf16 B*O*256 = 67 MB) lives in the out_obj region (dead until obj_mlp)
  unsigned short* objSO = (unsigned short*)d_out;

  char* ws = (char*)d_ws;
  // ws layout (all within proven 132 MB):
  //   0        .. 229376  : w1t/w2t/w3t/w4t (bf16)
  //   262144   .. 524288  : hist (u16, B*O)
  //   524288   .. 1048576 : offs (i32, B*O, global positions)
  //   1048576  .. 3145728 : es4  (u32, B*T: t | s<<16)
  //   3145728  .. 4194304 : osort(u16, B*T)
  //   4194304  .. +128MB  : partial (bf16, B*T x 128, sparse)
  short* w1t = (short*)(ws);
  short* w2t = (short*)(ws + 49152 * 2);
  short* w3t = (short*)(ws + (49152 + 32768) * 2);
  short* w4t = (short*)(ws + (49152 + 32768 + 16384) * 2);
  unsigned short* hist = (unsigned short*)(ws + 262144);
  int* offs = (int*)(ws + 524288);
  uint32_t* es4 = (uint32_t*)(ws + 1048576);
  unsigned short* osort = (unsigned short*)(ws + 3145728);
  unsigned short* partial = (unsigned short*)(ws + 4194304);

  prep_weights<<<448, 256, 0, stream>>>(W1, W2, W3, W4, w1t, w2t, w3t, w4t);
  sort_kernel<<<Bn, 1024, 0, stream>>>(edges, hist, offs, es4, osort);
  objproj<<<512, 512, 0, stream>>>(obj, w1t, objSO);
  edge_mlp<<<256, 512, 0, stream>>>(pred, es4, osort, objSO, w1t, w2t,
      b1, g1, be1, b2, g2, be2, out_p, partial);
  obj_mlp<<<(Bn * On) / 64, 256, 0, stream>>>(partial, hist, offs, out_obj,
      w3t, w4t, b3, g3, be3, b4, g4, be4);
}

// Round 9
// 324.357 us; speedup vs baseline: 2.7760x; 1.4930x over previous
//
#include <hip/hip_runtime.h>
#include <hip/hip_bf16.h>
#include <stdint.h>

// GraphTripleConv: B=32, O=4096, T=16384, D=H=DOUT=128
// out = [new_obj (B*O*128) | new_p (B*T*128)], f32
#define Bn 32
#define On 4096
#define Tn 16384
#define Dn 128

typedef short short8 __attribute__((ext_vector_type(8)));
typedef float f32x4 __attribute__((ext_vector_type(4)));

__device__ inline short f2bf(float f) {
  union { float f; uint32_t u; } v; v.f = f;
  uint32_t u = v.u;
  uint32_t r = u + 0x7fffu + ((u >> 16) & 1u);  // RNE
  return (short)(r >> 16);
}
__device__ inline float bf2f(unsigned short u) {
  union { uint32_t ui; float f; } cv; cv.ui = ((uint32_t)u) << 16; return cv.f;
}

// raw barrier: drains LDS ops only; global loads/stores stay in flight (no vmcnt(0))
#define LBAR() do { \
  asm volatile("s_waitcnt lgkmcnt(0)" ::: "memory"); \
  __builtin_amdgcn_sched_barrier(0); \
  __builtin_amdgcn_s_barrier(); \
} while (0)

// ---- weight prep: f32 [K][N] -> bf16 [N][K] (transposed)
__global__ void prep_weights(const float* __restrict__ W1, const float* __restrict__ W2,
                             const float* __restrict__ W3, const float* __restrict__ W4,
                             short* __restrict__ w1t, short* __restrict__ w2t,
                             short* __restrict__ w3t, short* __restrict__ w4t) {
  int i = blockIdx.x * 256 + threadIdx.x;
  if (i < 49152) {
    int n = i / 384, k = i % 384;
    w1t[i] = f2bf(W1[k * 128 + n]);
  } else if (i < 49152 + 32768) {
    int j = i - 49152;
    int n = j / 128, k = j % 128;
    w2t[j] = f2bf(W2[k * 384 + 128 + n]);   // only cols 128..383 live (new_s dead)
  } else if (i < 49152 + 32768 + 16384) {
    int j = i - 81920;
    int n = j / 128, k = j % 128;
    w3t[j] = f2bf(W3[k * 128 + n]);
  } else if (i < 114688) {
    int j = i - 98304;
    int n = j / 128, k = j % 128;
    w4t[j] = f2bf(W4[k * 128 + n]);
  }
}

// ---- fused counting sort: per-batch hist+scan+scatter entirely in LDS
__global__ __launch_bounds__(1024) void sort_kernel(
    const int* __restrict__ edges, int* __restrict__ hist_g,
    int* __restrict__ offs_g, unsigned short* __restrict__ eidx)
{
  __shared__ int h[4096];
  __shared__ int of[4096];
  __shared__ int sd[1024];
  int b = blockIdx.x, tid = threadIdx.x;
#pragma unroll
  for (int i = 0; i < 4; i++) h[tid + i * 1024] = 0;
  __syncthreads();
  int ov[16];
#pragma unroll
  for (int j = 0; j < 16; j++) {
    int t = j * 1024 + tid;
    ov[j] = edges[((size_t)(b * Tn + t)) * 2 + 1];
    atomicAdd(&h[ov[j]], 1);
  }
  __syncthreads();
  int base = tid * 4;
  int hh[4]; int s = 0;
#pragma unroll
  for (int j = 0; j < 4; j++) { hh[j] = h[base + j]; s += hh[j]; }
  sd[tid] = s;
  int tsum = s;
  for (int off = 1; off < 1024; off <<= 1) {
    __syncthreads();
    int t = (tid >= off) ? sd[tid - off] : 0;
    __syncthreads();
    sd[tid] += t;
  }
  __syncthreads();
  int excl = sd[tid] - tsum + b * Tn;
#pragma unroll
  for (int j = 0; j < 4; j++) {
    of[base + j] = excl;
    offs_g[b * On + base + j] = excl;
    hist_g[b * On + base + j] = hh[j];
    excl += hh[j];
  }
  __syncthreads();
#pragma unroll
  for (int i = 0; i < 4; i++) h[tid + i * 1024] = 0;   // reuse as fill
  __syncthreads();
#pragma unroll
  for (int j = 0; j < 16; j++) {
    int t = j * 1024 + tid;
    int pos = of[ov[j]] + atomicAdd(&h[ov[j]], 1);
    eidx[pos] = (unsigned short)t;
  }
}

// ---- object projection (persistent weights): objSO[r] = [obj[r]@W1s | obj[r]@W1o], bf16
__global__ __launch_bounds__(512, 2) void objproj(
    const float* __restrict__ obj, const short* __restrict__ w1t,
    unsigned short* __restrict__ objSO)
{
  __shared__ __align__(16) char lds[81920];
  const int WOF = 0, AOF = 65536;
  int tid = threadIdx.x;
  {
    int n = tid >> 2, q = tid & 3;
    int swz = (n & 7) << 4;
    const short* s1 = w1t + n * 384 + q * 32;          // W1s: k 0..127
    const short* s2 = w1t + n * 384 + 256 + q * 32;    // W1o: k 256..383
#pragma unroll
    for (int i = 0; i < 4; i++) {
      *(short8*)(lds + WOF + n * 256 + ((q * 64 + i * 16) ^ swz)) = *(const short8*)(s1 + i * 8);
      *(short8*)(lds + WOF + 32768 + n * 256 + ((q * 64 + i * 16) ^ swz)) = *(const short8*)(s2 + i * 8);
    }
  }
  int wave = tid >> 6, lane = tid & 63;
  int l15 = lane & 15, l4 = lane >> 4;
  int mg = wave >> 2, ng = wave & 3;
  int r = tid >> 3, seg = tid & 7;
  int rswz = (r & 7) << 4;

  for (int it = 0; it < 4; it++) {
    int row0 = (blockIdx.x * 4 + it) * 64;
    if (it) __syncthreads();
    {
      const float* src = obj + (size_t)(row0 + r) * Dn + seg * 16;
      float4 v0 = *(const float4*)(src);
      float4 v1 = *(const float4*)(src + 4);
      float4 v2 = *(const float4*)(src + 8);
      float4 v3 = *(const float4*)(src + 12);
      short8 p0, p1;
      p0[0]=f2bf(v0.x); p0[1]=f2bf(v0.y); p0[2]=f2bf(v0.z); p0[3]=f2bf(v0.w);
      p0[4]=f2bf(v1.x); p0[5]=f2bf(v1.y); p0[6]=f2bf(v1.z); p0[7]=f2bf(v1.w);
      p1[0]=f2bf(v2.x); p1[1]=f2bf(v2.y); p1[2]=f2bf(v2.z); p1[3]=f2bf(v2.w);
      p1[4]=f2bf(v3.x); p1[5]=f2bf(v3.y); p1[6]=f2bf(v3.z); p1[7]=f2bf(v3.w);
      *(short8*)(lds + AOF + r * 256 + ((seg * 32) ^ rswz)) = p0;
      *(short8*)(lds + AOF + r * 256 + ((seg * 32 + 16) ^ rswz)) = p1;
    }
    __syncthreads();
#pragma unroll
    for (int half = 0; half < 2; half++) {
      f32x4 acc[2][2] = {};
#pragma unroll
      for (int kk = 0; kk < 4; kk++) {
        short8 a[2], bb[2];
#pragma unroll
        for (int m = 0; m < 2; m++) {
          int row = mg * 32 + m * 16 + l15;
          a[m] = *(short8*)(lds + AOF + row * 256 + ((kk * 64 + 16 * l4) ^ ((row & 7) << 4)));
        }
#pragma unroll
        for (int n = 0; n < 2; n++) {
          int nr = ng * 32 + n * 16 + l15;
          bb[n] = *(short8*)(lds + WOF + half * 32768 + nr * 256 + ((kk * 64 + 16 * l4) ^ ((nr & 7) << 4)));
        }
#pragma unroll
        for (int m = 0; m < 2; m++)
#pragma unroll
          for (int n = 0; n < 2; n++)
            acc[m][n] = __builtin_amdgcn_mfma_f32_16x16x32_bf16(a[m], bb[n], acc[m][n], 0, 0, 0);
      }
#pragma unroll
      for (int n = 0; n < 2; n++) {
        int col = ng * 32 + n * 16 + l15;
#pragma unroll
        for (int m = 0; m < 2; m++)
#pragma unroll
          for (int rr = 0; rr < 4; rr++) {
            int row = mg * 32 + m * 16 + l4 * 4 + rr;
            objSO[(size_t)(row0 + row) * 256 + half * 128 + col] =
                (unsigned short)f2bf(acc[m][n][rr]);
          }
      }
    }
  }
}

// ---- edge MLP v9: r6 structure + separate h1 buffer (2 barriers/tile) + lgkm-only
// barriers so prefetch loads stay in flight across tiles.
// grid 256 (1 block/CU), 512 thr, 32 consecutive 64-row tiles per block.
// LDS 144KB: w1p 32K + w2 64K resident; A 16K; H 16K; G 16K.
#define ENT 32
__global__ __launch_bounds__(512, 2) void edge_mlp(
    const float* __restrict__ pred, const int* __restrict__ edges,
    const unsigned short* __restrict__ objSO,
    const short* __restrict__ w1t, const short* __restrict__ w2t,
    const float* __restrict__ b1, const float* __restrict__ g1, const float* __restrict__ be1,
    const float* __restrict__ b2, const float* __restrict__ g2, const float* __restrict__ be2,
    float* __restrict__ out_p, unsigned short* __restrict__ o_scr)
{
  __shared__ __align__(16) char lds[147456];
  const int W1P = 0;        // 32K: w1p rows 0..127 x 256B swz
  const int W2O = 32768;    // 64K: w2  rows 0..255 x 256B swz
  const int ABUF = 98304;   // 16K: A tile (bf16 swz)
  const int HBUF = 114688;  // 16K: h1 (bf16 swz)
  const int GOF = 131072;   // 16K: g = objS[s]+objO[o]

  const float invs = 1.0f / sqrtf(1.001f);
  int tid = threadIdx.x;

  // resident weights (once per block)
  {
    int n = tid >> 2, q = tid & 3;
    int swz = (n & 7) << 4;
    const short* src = w1t + n * 384 + 128 + q * 32;
#pragma unroll
    for (int i = 0; i < 4; i++)
      *(short8*)(lds + W1P + n * 256 + ((q * 64 + i * 16) ^ swz)) = *(const short8*)(src + i * 8);
  }
  {
    int n = tid >> 1, q = tid & 1;
    int swz = (n & 7) << 4;
    const short* src = w2t + n * 128 + q * 64;
#pragma unroll
    for (int i = 0; i < 8; i++)
      *(short8*)(lds + W2O + n * 256 + ((q * 128 + i * 16) ^ swz)) = *(const short8*)(src + i * 8);
  }

  int r = tid >> 3, seg = tid & 7;
  int rswz = (r & 7) << 4;

  float4 pv0, pv1, pv2, pv3;
  short8 sv0, sv1, ov0, ov1;

  auto load_tile = [&](int gt) {
    int b_ = gt >> 8;
    int t = ((gt & 255) << 6) + r;
    const float* src = pred + ((size_t)(b_ * Tn + t)) * Dn + seg * 16;
    pv0 = *(const float4*)(src);
    pv1 = *(const float4*)(src + 4);
    pv2 = *(const float4*)(src + 8);
    pv3 = *(const float4*)(src + 12);
    int2 e = *(const int2*)&edges[((size_t)(b_ * Tn + t)) * 2];
    const unsigned short* srow = objSO + ((size_t)(b_ * On + e.x)) * 256 + seg * 16;
    const unsigned short* orow = objSO + ((size_t)(b_ * On + e.y)) * 256 + 128 + seg * 16;
    sv0 = *(const short8*)(srow);
    sv1 = *(const short8*)(srow + 8);
    ov0 = *(const short8*)(orow);
    ov1 = *(const short8*)(orow + 8);
  };

  auto store_stage = [&]() {
    short8 p0, p1;
    p0[0]=f2bf(pv0.x); p0[1]=f2bf(pv0.y); p0[2]=f2bf(pv0.z); p0[3]=f2bf(pv0.w);
    p0[4]=f2bf(pv1.x); p0[5]=f2bf(pv1.y); p0[6]=f2bf(pv1.z); p0[7]=f2bf(pv1.w);
    p1[0]=f2bf(pv2.x); p1[1]=f2bf(pv2.y); p1[2]=f2bf(pv2.z); p1[3]=f2bf(pv2.w);
    p1[4]=f2bf(pv3.x); p1[5]=f2bf(pv3.y); p1[6]=f2bf(pv3.z); p1[7]=f2bf(pv3.w);
    *(short8*)(lds + ABUF + r * 256 + ((seg * 32) ^ rswz)) = p0;
    *(short8*)(lds + ABUF + r * 256 + ((seg * 32 + 16) ^ rswz)) = p1;
    short8 g0, g1v;
#pragma unroll
    for (int j = 0; j < 8; j++) {
      g0[j]  = f2bf(bf2f((unsigned short)sv0[j]) + bf2f((unsigned short)ov0[j]));
      g1v[j] = f2bf(bf2f((unsigned short)sv1[j]) + bf2f((unsigned short)ov1[j]));
    }
    *(short8*)(lds + GOF + r * 256 + ((seg * 32) ^ rswz)) = g0;
    *(short8*)(lds + GOF + r * 256 + ((seg * 32 + 16) ^ rswz)) = g1v;
  };

  int tile0 = blockIdx.x * ENT;
  int wave = tid >> 6, lane = tid & 63;
  int l15 = lane & 15, l4 = lane >> 4;
  int mg = wave >> 2, ng = wave & 3;

  // prologue: stage tile 0; hold tile 1 in registers
  load_tile(tile0);
  store_stage();
  load_tile(tile0 + 1);
  LBAR();

  for (int k = 0; k < ENT; ++k) {
    int gt = tile0 + k;
    int b_ = gt >> 8, t0v = (gt & 255) << 6;

    // ---- P1: GEMM1 (A @ w1p, wave 32x32) then epi1 -> HBUF (reads GOF)
    f32x4 acc1[2][2] = {};
#pragma unroll
    for (int kk = 0; kk < 4; kk++) {
      short8 a[2], bb[2];
#pragma unroll
      for (int m = 0; m < 2; m++) {
        int row = mg * 32 + m * 16 + l15;
        a[m] = *(short8*)(lds + ABUF + row * 256 + ((kk * 64 + 16 * l4) ^ ((row & 7) << 4)));
      }
#pragma unroll
      for (int n = 0; n < 2; n++) {
        int nr = ng * 32 + n * 16 + l15;
        bb[n] = *(short8*)(lds + W1P + nr * 256 + ((kk * 64 + 16 * l4) ^ ((nr & 7) << 4)));
      }
#pragma unroll
      for (int m = 0; m < 2; m++)
#pragma unroll
        for (int n = 0; n < 2; n++)
          acc1[m][n] = __builtin_amdgcn_mfma_f32_16x16x32_bf16(a[m], bb[n], acc1[m][n], 0, 0, 0);
    }
#pragma unroll
    for (int n = 0; n < 2; n++) {
      int col = ng * 32 + n * 16 + l15;
      float gs = g1[col] * invs;
      float add = b1[col] * gs + be1[col];
#pragma unroll
      for (int m = 0; m < 2; m++)
#pragma unroll
        for (int rr = 0; rr < 4; rr++) {
          int row = mg * 32 + m * 16 + l4 * 4 + rr;
          float gv = bf2f(*(const unsigned short*)(lds + GOF + row * 256 + ((col * 2) ^ ((row & 7) << 4))));
          float v = fmaxf((acc1[m][n][rr] + gv) * gs + add, 0.0f);
          *(short*)(lds + HBUF + row * 256 + ((col * 2) ^ ((row & 7) << 4))) = f2bf(v);
        }
    }
    LBAR();   // B1: A/G reads + H writes settled

    // ---- P2: stage tile k+1 into A/G (regs loaded a full tile ago);
    //          issue loads for tile k+2 (stay in flight across barriers)
    if (k + 1 < ENT) store_stage();
    if (k + 2 < ENT) load_tile(tile0 + k + 2);

    // ---- GEMM2: h1(HBUF) @ w2 (wave 32x64), epilogue stores
    f32x4 acc2[2][4] = {};
#pragma unroll
    for (int kk = 0; kk < 4; kk++) {
      short8 a[2], bb[4];
#pragma unroll
      for (int m = 0; m < 2; m++) {
        int row = mg * 32 + m * 16 + l15;
        a[m] = *(short8*)(lds + HBUF + row * 256 + ((kk * 64 + 16 * l4) ^ ((row & 7) << 4)));
      }
#pragma unroll
      for (int n = 0; n < 4; n++) {
        int nr = ng * 64 + n * 16 + l15;
        bb[n] = *(short8*)(lds + W2O + nr * 256 + ((kk * 64 + 16 * l4) ^ ((nr & 7) << 4)));
      }
#pragma unroll
      for (int m = 0; m < 2; m++)
#pragma unroll
        for (int n = 0; n < 4; n++)
          acc2[m][n] = __builtin_amdgcn_mfma_f32_16x16x32_bf16(a[m], bb[n], acc2[m][n], 0, 0, 0);
    }
#pragma unroll
    for (int n = 0; n < 4; n++) {
      int colp = ng * 64 + n * 16 + l15;   // 0..255
      int c2 = 128 + colp;
      float gs = g2[c2] * invs;
      float add = b2[c2] * gs + be2[c2];
#pragma unroll
      for (int m = 0; m < 2; m++)
#pragma unroll
        for (int rr = 0; rr < 4; rr++) {
          int row = mg * 32 + m * 16 + l4 * 4 + rr;
          float v = fmaxf(acc2[m][n][rr] * gs + add, 0.0f);
          if (colp < 128) {
            out_p[(size_t)(b_ * Tn + t0v + row) * 128 + colp] = v;
          } else {
            o_scr[(size_t)(b_ * Tn + t0v + row) * 128 + (colp - 128)] =
                (unsigned short)f2bf(v);
          }
        }
    }
    LBAR();   // B2: H reads done; staged A/G visible for next tile
  }
}

// ---- object MLP (pooling fused, reg weights): gather-mean from o_scr, GEMM3 -> GEMM4
__global__ __launch_bounds__(256) void obj_mlp(
    const unsigned short* __restrict__ o_scr, const int* __restrict__ hist,
    const int* __restrict__ offs, const unsigned short* __restrict__ eidx,
    float* __restrict__ out_obj,
    const short* __restrict__ w3t, const short* __restrict__ w4t,
    const float* __restrict__ b3, const float* __restrict__ g3, const float* __restrict__ be3,
    const float* __restrict__ b4, const float* __restrict__ g4, const float* __restrict__ be4)
{
  __shared__ short xs[64][136];
  __shared__ short hs[64][136];
  const float invs = 1.0f / sqrtf(1.001f);
  int row0 = blockIdx.x * 64;
  int tid = threadIdx.x;

  {
    int r = tid >> 2, seg = tid & 3;
    int rg = row0 + r;
    int bb_ = rg >> 12;
    int cnt = hist[rg], start = offs[rg];
    float sum[32];
#pragma unroll
    for (int j = 0; j < 32; j++) sum[j] = 0.f;
    for (int k = 0; k < cnt; k++) {
      int t = eidx[start + k];
      const unsigned short* src = o_scr + ((size_t)(bb_ * Tn + t)) * 128 + seg * 32;
#pragma unroll
      for (int i = 0; i < 4; i++) {
        short8 v = *(const short8*)(src + i * 8);
#pragma unroll
        for (int j = 0; j < 8; j++) sum[i * 8 + j] += bf2f((unsigned short)v[j]);
      }
    }
    float ic = 1.0f / fmaxf((float)cnt, 1.0f);
#pragma unroll
    for (int i = 0; i < 4; i++) {
      short8 pk;
#pragma unroll
      for (int j = 0; j < 8; j++) pk[j] = f2bf(sum[i * 8 + j] * ic);
      *(short8*)&xs[r][seg * 32 + i * 8] = pk;
    }
  }
  __syncthreads();

  int wave = tid >> 6, lane = tid & 63;
  int l15 = lane & 15, l4 = lane >> 4;
  int n0 = wave * 32;

  short8 w3r[2][4], w4r[2][4];
#pragma unroll
  for (int n = 0; n < 2; n++)
#pragma unroll
    for (int kk = 0; kk < 4; kk++) {
      w3r[n][kk] = *(const short8*)&w3t[(n0 + n * 16 + l15) * 128 + kk * 32 + 8 * l4];
      w4r[n][kk] = *(const short8*)&w4t[(n0 + n * 16 + l15) * 128 + kk * 32 + 8 * l4];
    }

  f32x4 acc[4][2] = {};
#pragma unroll
  for (int kk = 0; kk < 4; kk++) {
    int k0 = kk * 32;
    short8 a[4];
#pragma unroll
    for (int m = 0; m < 4; m++) a[m] = *(short8*)&xs[m * 16 + l15][k0 + 8 * l4];
#pragma unroll
    for (int m = 0; m < 4; m++)
#pragma unroll
      for (int n = 0; n < 2; n++)
        acc[m][n] = __builtin_amdgcn_mfma_f32_16x16x32_bf16(a[m], w3r[n][kk], acc[m][n], 0, 0, 0);
  }
#pragma unroll
  for (int n = 0; n < 2; n++) {
    int col = n0 + n * 16 + l15;
    float gs = g3[col] * invs;
    float add = b3[col] * gs + be3[col];
#pragma unroll
    for (int m = 0; m < 4; m++)
#pragma unroll
      for (int rr = 0; rr < 4; rr++) {
        float v = fmaxf(acc[m][n][rr] * gs + add, 0.0f);
        hs[m * 16 + l4 * 4 + rr][col] = f2bf(v);
      }
  }
  __syncthreads();

  f32x4 acc2[4][2] = {};
#pragma unroll
  for (int kk = 0; kk < 4; kk++) {
    int k0 = kk * 32;
    short8 a[4];
#pragma unroll
    for (int m = 0; m < 4; m++) a[m] = *(short8*)&hs[m * 16 + l15][k0 + 8 * l4];
#pragma unroll
    for (int m = 0; m < 4; m++)
#pragma unroll
      for (int n = 0; n < 2; n++)
        acc2[m][n] = __builtin_amdgcn_mfma_f32_16x16x32_bf16(a[m], w4r[n][kk], acc2[m][n], 0, 0, 0);
  }
#pragma unroll
  for (int n = 0; n < 2; n++) {
    int col = n0 + n * 16 + l15;
    float gs = g4[col] * invs;
    float add = b4[col] * gs + be4[col];
#pragma unroll
    for (int m = 0; m < 4; m++)
#pragma unroll
      for (int rr = 0; rr < 4; rr++) {
        int row = m * 16 + l4 * 4 + rr;
        float v = fmaxf(acc2[m][n][rr] * gs + add, 0.0f);
        out_obj[(size_t)(row0 + row) * 128 + col] = v;
      }
  }
}

extern "C" void kernel_launch(void* const* d_in, const int* in_sizes, int n_in,
                              void* d_out, int out_size, void* d_ws, size_t ws_size,
                              hipStream_t stream) {
  const float* obj  = (const float*)d_in[0];
  const float* pred = (const float*)d_in[1];
  const int*   edges= (const int*)d_in[2];
  const float* W1 = (const float*)d_in[3];
  const float* b1 = (const float*)d_in[4];
  const float* g1 = (const float*)d_in[5];
  const float* be1= (const float*)d_in[6];
  const float* W2 = (const float*)d_in[7];
  const float* b2 = (const float*)d_in[8];
  const float* g2 = (const float*)d_in[9];
  const float* be2= (const float*)d_in[10];
  const float* W3 = (const float*)d_in[11];
  const float* b3 = (const float*)d_in[12];
  const float* g3 = (const float*)d_in[13];
  const float* be3= (const float*)d_in[14];
  const float* W4 = (const float*)d_in[15];
  const float* b4 = (const float*)d_in[16];
  const float* g4 = (const float*)d_in[17];
  const float* be4= (const float*)d_in[18];

  float* out_obj = (float*)d_out;                           // B*O*128
  float* out_p   = (float*)d_out + (size_t)Bn * On * 128;   // B*T*128
  // objSO (bf16 B*O*256 = 67 MB) lives in the out_obj region (dead until obj_mlp)
  unsigned short* objSO = (unsigned short*)d_out;

  char* ws = (char*)d_ws;
  short* w1t = (short*)(ws);
  short* w2t = (short*)(ws + 49152 * 2);
  short* w3t = (short*)(ws + (49152 + 32768) * 2);
  short* w4t = (short*)(ws + (49152 + 32768 + 16384) * 2);

  const size_t OFF_HIST = 262144;
  const size_t OFF_OFFS = OFF_HIST + 524288;
  const size_t OFF_EIDX = OFF_OFFS + 1048576;     // u16 B*T = 1 MB
  const size_t OFF_OSCR = 4194304;                // bf16 B*T*128 = 128 MiB

  int* hist = (int*)(ws + OFF_HIST);
  int* offs = (int*)(ws + OFF_OFFS);
  unsigned short* eidx = (unsigned short*)(ws + OFF_EIDX);
  unsigned short* o_scr = (unsigned short*)(ws + OFF_OSCR);

  prep_weights<<<448, 256, 0, stream>>>(W1, W2, W3, W4, w1t, w2t, w3t, w4t);
  sort_kernel<<<Bn, 1024, 0, stream>>>(edges, hist, offs, eidx);
  objproj<<<512, 512, 0, stream>>>(obj, w1t, objSO);
  edge_mlp<<<256, 512, 0, stream>>>(pred, edges, objSO, w1t, w2t,
      b1, g1, be1, b2, g2, be2, out_p, o_scr);
  obj_mlp<<<(Bn * On) / 64, 256, 0, stream>>>(o_scr, hist, offs, eidx, out_obj,
      w3t, w4t, b3, g3, be3, b4, g4, be4);
}